// Round 8
// baseline (736.386 us; speedup 1.0000x reference)
//
#include <hip/hip_runtime.h>

#define BB 4096
#define AA_ 32
#define OBSD 128
#define HIDD 256
#define MSGD 64
#define NHH 4
#define DHH 16
#define NACTD 16
#define NT 512

// workspace pre-split weight layout (element offsets; hi at [i], lo at [WS_TOTAL+i])
#define OFF_WLOCAL 0
#define OFF_WINTER 32768
#define OFF_WINTRA 40960
#define OFF_WQKV   49152
#define OFF_WO     98304
#define OFF_W1     114688
#define OFF_W2     212992
#define OFF_WA     278528
#define OFF_WHEAD  282624   // augmented head [32][256]: rows 0-15 Wa, 16 Wv, 17-31 zero
#define WS_TOTAL   290816

// LDS arena (bytes), total 49664 -> 3 blocks/CU.
//  L_LB 0      localb [32][264] 16896   (h2 in P5->P6)
//  L_IE 16896  intra_e [32][72] (nets0-1) | nobs (net2/3 -> pooling) | alog [32][18]f32 (P6)
//  L_NE 21504  inter_e [32][72] (nets2-3)
//  L_IO 26112  iobs [32][72]
//  L_QK 30720  qk [32][136] (q 0-63, k 64-127, 128-135 ZEROED pad) | xh (P1) | hb (P4->P5)
//  L_VT 39424  vT [64][40] | xl (P1)
//  L_AT 44544  atto [32][72]
//  L_SC 49152  pooled_hi[64]u16, pooled_lo[64]u16, plog[32]f32, pscore[32]f32
#define L_LB 0
#define L_IE 16896
#define L_NE 21504
#define L_IO 26112
#define L_QK 30720
#define L_VT 39424
#define L_AT 44544
#define L_SC 49152
#define SMEM_SZ 49664

typedef unsigned short u16;
typedef unsigned int u32;
typedef __attribute__((ext_vector_type(8))) short bf16x8;
typedef __attribute__((ext_vector_type(4))) float f32x4;

#define MFMA16(a, b, c) __builtin_amdgcn_mfma_f32_16x16x32_bf16((a), (b), (c), 0, 0, 0)

__device__ __forceinline__ float b2f(u16 s) { return __uint_as_float((u32)s << 16); }
__device__ __forceinline__ u16 f2b(float f) {
    u32 u = __float_as_uint(f);
    u += 0x7FFFu + ((u >> 16) & 1u);   // round-to-nearest-even
    return (u16)(u >> 16);
}
__device__ __forceinline__ float tof(float x) { return x; }
__device__ __forceinline__ float tof(u16 x) { return b2f(x); }
template<typename T> __device__ __forceinline__ T fromf(float v);
template<> __device__ __forceinline__ float fromf<float>(float v) { return v; }
template<> __device__ __forceinline__ u16 fromf<u16>(float v) { return f2b(v); }

__device__ __forceinline__ bf16x8 bzero8() { bf16x8 v = {0,0,0,0,0,0,0,0}; return v; }

// fast tanh: err ~1e-6, far below bf16 storage quantum
__device__ __forceinline__ float fast_tanh(float x) {
    float ax = fabsf(x);
    float e = __expf(-2.f * ax);
    float t = (1.f - e) * __builtin_amdgcn_rcpf(1.f + e);
    return copysignf(t, x);
}

// Weight fragment loader. WM: 0 = bf16 direct (T=u16), 1 = f32 self-split (T=float),
// 2 = pre-split hi/lo from workspace. hi/lo give ~f32 weight precision via 2 MFMAs.
template<int WM, typename T>
__device__ __forceinline__ void loadW(const T* Wf, const u16* Whi, const u16* Wlo,
                                      int ldw, int n, int k, bf16x8& bh, bf16x8& bl) {
    if constexpr (WM == 0) {
        bh = *(const bf16x8*)((const u16*)Wf + (size_t)n * ldw + k);
    } else if constexpr (WM == 2) {
        bh = *(const bf16x8*)(Whi + (size_t)n * ldw + k);
        bl = *(const bf16x8*)(Wlo + (size_t)n * ldw + k);
    } else {
        const float* p = (const float*)Wf + (size_t)n * ldw + k;
        f32x4 f0 = *(const f32x4*)(p);
        f32x4 f1 = *(const f32x4*)(p + 4);
#pragma unroll
        for (int j = 0; j < 8; j++) {
            float fv = (j < 4) ? f0[j] : f1[j - 4];
            u16 h = f2b(fv);
            bh[j] = (short)h;
            bl[j] = (short)f2b(fv - b2f(h));
        }
    }
}

// O[0..31][0..N) = act(X[32xK] @ W^T + bias); X in LDS bf16 (stride ldx), W [N][K].
// nt loop kept rolled (#pragma unroll 1): I-cache footprint control.
template<int N, int K, int ACT, int WM, typename T>
__device__ __forceinline__ void mdense(const u16* X, int ldx,
                                       const T* Wf, const u16* Whi, const u16* Wlo,
                                       const T* bias, u16* O, int ldo) {
    const int tid = threadIdx.x;
    const int wv = tid >> 6, lo16 = tid & 15, hi = (tid & 63) >> 4;
#pragma unroll 1
    for (int nt = wv; nt < N / 16; nt += 8) {
        f32x4 acc0 = {0.f, 0.f, 0.f, 0.f}, acc1 = {0.f, 0.f, 0.f, 0.f};
#pragma unroll
        for (int k0 = 0; k0 < K; k0 += 32) {
            bf16x8 bh, bl;
            loadW<WM>(Wf, Whi, Wlo, K, nt * 16 + lo16, k0 + hi * 8, bh, bl);
            bf16x8 a0 = *(const bf16x8*)(X + lo16 * ldx + k0 + hi * 8);
            bf16x8 a1 = *(const bf16x8*)(X + (16 + lo16) * ldx + k0 + hi * 8);
            acc0 = MFMA16(a0, bh, acc0);
            acc1 = MFMA16(a1, bh, acc1);
            if constexpr (WM != 0) {
                acc0 = MFMA16(a0, bl, acc0);
                acc1 = MFMA16(a1, bl, acc1);
            }
        }
        float bb = tof(bias[nt * 16 + lo16]);
#pragma unroll
        for (int r = 0; r < 4; r++) {
            float v0 = acc0[r] + bb, v1 = acc1[r] + bb;
            if (ACT) { v0 = fast_tanh(v0); v1 = fast_tanh(v1); }
            O[(hi * 4 + r) * ldo + nt * 16 + lo16] = f2b(v0);
            O[(16 + hi * 4 + r) * ldo + nt * 16 + lo16] = f2b(v1);
        }
    }
}

// QKV pass for one net: q,k -> qk[row][col]; v -> transposed vT[d][row].
template<int WM, typename T>
__device__ __forceinline__ void qkv_pass(int net, const u16* xe,
                                         const T* Wqkv, const T* bqkv,
                                         const u16* wsh, const u16* wsl,
                                         u16* qk, u16* vT) {
    const int tid = threadIdx.x;
    const int wv = tid >> 6, lo16 = tid & 15, hi = (tid & 63) >> 4;
    const T* Wq = Wqkv + (size_t)net * 192 * MSGD;
    const T* bq_ = bqkv + (size_t)net * 192;
    const u16* Whi = (WM == 2) ? wsh + OFF_WQKV + net * 192 * MSGD : nullptr;
    const u16* Wlo = (WM == 2) ? wsl + OFF_WQKV + net * 192 * MSGD : nullptr;
#pragma unroll 1
    for (int nt = wv; nt < 12; nt += 8) {
        f32x4 acc0 = {0.f, 0.f, 0.f, 0.f}, acc1 = {0.f, 0.f, 0.f, 0.f};
#pragma unroll
        for (int k0 = 0; k0 < 64; k0 += 32) {
            bf16x8 bh, bl;
            loadW<WM>(Wq, Whi, Wlo, 64, nt * 16 + lo16, k0 + hi * 8, bh, bl);
            bf16x8 a0 = *(const bf16x8*)(xe + lo16 * 72 + k0 + hi * 8);
            bf16x8 a1 = *(const bf16x8*)(xe + (16 + lo16) * 72 + k0 + hi * 8);
            acc0 = MFMA16(a0, bh, acc0);
            acc1 = MFMA16(a1, bh, acc1);
            if constexpr (WM != 0) {
                acc0 = MFMA16(a0, bl, acc0);
                acc1 = MFMA16(a1, bl, acc1);
            }
        }
        float bb = tof(bq_[nt * 16 + lo16]);
        if (nt < 8) {
#pragma unroll
            for (int r = 0; r < 4; r++) {
                qk[(hi * 4 + r) * 136 + nt * 16 + lo16] = f2b(acc0[r] + bb);
                qk[(16 + hi * 4 + r) * 136 + nt * 16 + lo16] = f2b(acc1[r] + bb);
            }
        } else {
            const int d = (nt - 8) * 16 + lo16;
#pragma unroll
            for (int r = 0; r < 4; r++) {
                vT[d * 40 + hi * 4 + r] = f2b(acc0[r] + bb);
                vT[d * 40 + 16 + hi * 4 + r] = f2b(acc1[r] + bb);
            }
        }
    }
}

template<typename T, int WM>
__device__ void body(const T* obs, const T* eps_intra, const T* eps_inter,
                     const T* W_local, const T* b_local,
                     const T* W_inter, const T* b_inter,
                     const T* W_intra, const T* b_intra,
                     const T* Wqkv, const T* bqkv, const T* Wo, const T* bo,
                     const T* att_w, const T* att_b,
                     const T* W1, const T* b1, const T* W2, const T* b2,
                     const T* Wa, const T* ba, const T* Wv, const T* bv,
                     T* out_a, T* out_v, char* smem, const u16* wsw) {
    constexpr bool XSPLIT = (sizeof(T) == 4);   // split activations (obs) hi/lo
    const int tid = threadIdx.x;
    const int b = blockIdx.x;
    const int wv = tid >> 6, lane = tid & 63, lo16 = lane & 15, hi = lane >> 4;

    const u16* wsh = wsw;
    const u16* wsl = (WM == 2) ? wsw + WS_TOTAL : nullptr;
#define WPAIR(OFF) ((WM == 2) ? wsh + (OFF) : nullptr), ((WM == 2) ? wsl + (OFF) : nullptr)

    u16* localb    = (u16*)(smem + L_LB);
    u16* intra_e   = (u16*)(smem + L_IE);
    u16* nobs      = (u16*)(smem + L_IE);
    float* alog    = (float*)(smem + L_IE);
    u16* inter_e   = (u16*)(smem + L_NE);
    u16* iobs      = (u16*)(smem + L_IO);
    u16* qk        = (u16*)(smem + L_QK);
    u16* xh        = (u16*)(smem + L_QK);
    u16* hb        = (u16*)(smem + L_QK);
    u16* vT        = (u16*)(smem + L_VT);
    u16* xl        = (u16*)(smem + L_VT);
    u16* atto      = (u16*)(smem + L_AT);
    u16* pooled_hi = (u16*)(smem + L_SC);
    u16* pooled_lo = (u16*)(smem + L_SC + 128);
    float* plog    = (float*)(smem + L_SC + 256);
    float* pscore  = (float*)(smem + L_SC + 384);

    // ---- P1a: stage obs -> LDS bf16 (hi + lo residual for fp32 inputs) ----
    {
        const T* ob = obs + (size_t)b * (AA_ * OBSD);
        const int i = tid;               // 512 groups of 8 == exactly NT
        const int row = i >> 4, col = (i & 15) * 8;
        if constexpr (XSPLIT) {
            f32x4 f0 = __builtin_nontemporal_load((const f32x4*)(ob + i * 8));
            f32x4 f1 = __builtin_nontemporal_load((const f32x4*)(ob + i * 8) + 1);
            bf16x8 vh, vl;
#pragma unroll
            for (int j = 0; j < 8; j++) {
                float fv = (j < 4) ? f0[j] : f1[j - 4];
                u16 h = f2b(fv);
                vh[j] = (short)h;
                vl[j] = (short)f2b(fv - b2f(h));
            }
            *(bf16x8*)(xh + row * 136 + col) = vh;
            *(bf16x8*)(xl + row * 136 + col) = vl;
        } else {
            bf16x8 v = __builtin_nontemporal_load((const bf16x8*)(ob + i * 8));
            *(bf16x8*)(xh + row * 136 + col) = v;
        }
        // CRITICAL: zero qk/xh pad columns 128..135. The fused-scores phase reads
        // A-fragments unconditionally (head 3, hi>=2 lanes hit these columns with
        // B=0); uninitialized LDS could decode as NaN/Inf -> 0*NaN = NaN in MFMA.
        // Nothing writes these pads during P2, so one zeroing persists for all nets.
        if (tid < 32) *(bf16x8*)(xh + tid * 136 + 128) = bzero8();
    }
    __syncthreads();

    // ---- P1b: local/intra/inter embeddings (24 tile-units over 8 waves) ----
#pragma unroll 1
    for (int u = wv; u < 24; u += 8) {
        const T *Wf, *bias; const u16 *Whi = nullptr, *Wlo = nullptr; u16* O; int ldo, nt;
        if (u < 16)      { Wf = W_local; bias = b_local; O = localb;  ldo = 264; nt = u;
                           if (WM == 2) { Whi = wsh + OFF_WLOCAL; Wlo = wsl + OFF_WLOCAL; } }
        else if (u < 20) { Wf = W_intra; bias = b_intra; O = intra_e; ldo = 72;  nt = u - 16;
                           if (WM == 2) { Whi = wsh + OFF_WINTRA; Wlo = wsl + OFF_WINTRA; } }
        else             { Wf = W_inter; bias = b_inter; O = inter_e; ldo = 72;  nt = u - 20;
                           if (WM == 2) { Whi = wsh + OFF_WINTER; Wlo = wsl + OFF_WINTER; } }
        f32x4 acc0 = {0.f, 0.f, 0.f, 0.f}, acc1 = {0.f, 0.f, 0.f, 0.f};
#pragma unroll
        for (int k0 = 0; k0 < OBSD; k0 += 32) {
            bf16x8 bh, bl;
            loadW<WM>(Wf, Whi, Wlo, OBSD, nt * 16 + lo16, k0 + hi * 8, bh, bl);
            bf16x8 a0 = *(const bf16x8*)(xh + lo16 * 136 + k0 + hi * 8);
            bf16x8 a1 = *(const bf16x8*)(xh + (16 + lo16) * 136 + k0 + hi * 8);
            acc0 = MFMA16(a0, bh, acc0);
            acc1 = MFMA16(a1, bh, acc1);
            if constexpr (WM != 0) {
                acc0 = MFMA16(a0, bl, acc0);
                acc1 = MFMA16(a1, bl, acc1);
            }
            if constexpr (XSPLIT) {
                bf16x8 l0 = *(const bf16x8*)(xl + lo16 * 136 + k0 + hi * 8);
                bf16x8 l1 = *(const bf16x8*)(xl + (16 + lo16) * 136 + k0 + hi * 8);
                acc0 = MFMA16(l0, bh, acc0);
                acc1 = MFMA16(l1, bh, acc1);
            }
        }
        float bb = tof(bias[nt * 16 + lo16]);
#pragma unroll
        for (int r = 0; r < 4; r++) {
            O[(hi * 4 + r) * ldo + nt * 16 + lo16] = f2b(fast_tanh(acc0[r] + bb));
            O[(16 + hi * 4 + r) * ldo + nt * 16 + lo16] = f2b(fast_tanh(acc1[r] + bb));
        }
    }
    __syncthreads();

    // ==== P2: 4 MHA nets (0:intra_mu 1:intra_std 2:inter_mu 3:inter_std).
    // Rolled loop (#pragma unroll 1): one code copy of {qkv | sPV | oproj}
    // instead of four -> ~4x smaller hot P2 code (I-cache). ====
#pragma unroll 1
    for (int net = 0; net < 4; net++) {
        qkv_pass<WM>(net, (net < 2) ? intra_e : inter_e, Wqkv, bqkv, wsh, wsl, qk, vT);
        __syncthreads();

        // fused scores + softmax + PV, one phase, no LDS P-matrix.
        // Transposed QK^T: mfma(K,Q) -> lane holds S[q=lo16][k in {4hi+r,16+4hi+r}].
        float epr[4] = {0.f, 0.f, 0.f, 0.f};
        {
            const int h = wv >> 1, mt = wv & 1;
            // prefetch eps for std-net outproj (consumed next phase)
            if (net == 1 || net == 3) {
                const T* epsb = ((net == 1) ? eps_intra : eps_inter) + (size_t)b * (AA_ * MSGD);
                const int ntU = wv & 3, half = wv >> 2, col = ntU * 16 + lo16;
#pragma unroll
                for (int r = 0; r < 4; r++)
                    epr[r] = tof(__builtin_nontemporal_load(epsb + (half * 16 + hi * 4 + r) * MSGD + col));
            }
            bf16x8 a0 = *(const bf16x8*)(qk + lo16 * 136 + 64 + h * 16 + hi * 8);
            bf16x8 a1 = *(const bf16x8*)(qk + (16 + lo16) * 136 + 64 + h * 16 + hi * 8);
            bf16x8 bq = bzero8();          // zero-pad dh 16->32 (B=0 kills k>=16 terms)
            if (hi < 2) bq = *(const bf16x8*)(qk + (mt * 16 + lo16) * 136 + h * 16 + hi * 8);
            f32x4 z = {0.f, 0.f, 0.f, 0.f};
            f32x4 sc0 = MFMA16(a0, bq, z);
            f32x4 sc1 = MFMA16(a1, bq, z);
            // softmax over k for row q=lo16: 8 in-lane values + 2 shfl_xor hops
            float v0[4], v1[4];
#pragma unroll
            for (int r = 0; r < 4; r++) { v0[r] = sc0[r] * 0.25f; v1[r] = sc1[r] * 0.25f; }
            float m = fmaxf(fmaxf(fmaxf(v0[0], v0[1]), fmaxf(v0[2], v0[3])),
                            fmaxf(fmaxf(v1[0], v1[1]), fmaxf(v1[2], v1[3])));
            m = fmaxf(m, __shfl_xor(m, 16));
            m = fmaxf(m, __shfl_xor(m, 32));
            float e0[4], e1[4], s = 0.f;
#pragma unroll
            for (int r = 0; r < 4; r++) {
                e0[r] = __expf(v0[r] - m); e1[r] = __expf(v1[r] - m);
                s += e0[r] + e1[r];
            }
            s += __shfl_xor(s, 16);
            s += __shfl_xor(s, 32);
            float inv = __builtin_amdgcn_rcpf(s);
            u32 pk0 = (u32)f2b(e0[0] * inv) | ((u32)f2b(e0[1] * inv) << 16);
            u32 pk1 = (u32)f2b(e0[2] * inv) | ((u32)f2b(e0[3] * inv) << 16);
            u32 pk2 = (u32)f2b(e1[0] * inv) | ((u32)f2b(e1[1] * inv) << 16);
            u32 pk3 = (u32)f2b(e1[2] * inv) | ((u32)f2b(e1[3] * inv) << 16);
            // assemble PV A-fragment: lane (q=lo16, hi) needs P[q][8hi..8hi+7]
            const int sA = (((hi * 2) & 3) << 4) | lo16;
            const int sB = sA + 16;
            u32 wA0 = __shfl(pk0, sA), wA1 = __shfl(pk1, sA);
            u32 wB0 = __shfl(pk0, sB), wB1 = __shfl(pk1, sB);
            u32 xA0 = __shfl(pk2, sA), xA1 = __shfl(pk3, sA);
            u32 xB0 = __shfl(pk2, sB), xB1 = __shfl(pk3, sB);
            const bool lo = (hi < 2);
            union { u32 w[4]; bf16x8 v; } pu;
            pu.w[0] = lo ? wA0 : xA0;
            pu.w[1] = lo ? wA1 : xA1;
            pu.w[2] = lo ? wB0 : xB0;
            pu.w[3] = lo ? wB1 : xB1;
            bf16x8 bv_ = *(const bf16x8*)(vT + (h * 16 + lo16) * 40 + hi * 8);
            f32x4 o = MFMA16(pu.v, bv_, z);
#pragma unroll
            for (int r = 0; r < 4; r++)
                atto[(mt * 16 + hi * 4 + r) * 72 + h * 16 + lo16] = f2b(o[r]);
        }
        __syncthreads();

        // out projection; mu nets write raw, std nets merge softplus*eps into target
        {
            const T* Won = Wo + (size_t)net * MSGD * MSGD;
            const T* bon = bo + (size_t)net * MSGD;
            const u16* Ohi = (WM == 2) ? wsh + OFF_WO + net * 4096 : nullptr;
            const u16* Olo = (WM == 2) ? wsl + OFF_WO + net * 4096 : nullptr;
            const int ntU = wv & 3, half = wv >> 2, col = ntU * 16 + lo16;
            f32x4 acc = {0.f, 0.f, 0.f, 0.f};
#pragma unroll
            for (int k0 = 0; k0 < 64; k0 += 32) {
                bf16x8 bh, bl;
                loadW<WM>(Won, Ohi, Olo, 64, col, k0 + hi * 8, bh, bl);
                bf16x8 a = *(const bf16x8*)(atto + (half * 16 + lo16) * 72 + k0 + hi * 8);
                acc = MFMA16(a, bh, acc);
                if constexpr (WM != 0) acc = MFMA16(a, bl, acc);
            }
            float bb = tof(bon[col]);
            u16* tgt = (net < 2) ? iobs : nobs;
#pragma unroll
            for (int r = 0; r < 4; r++) {
                const int row = half * 16 + hi * 4 + r;
                if (net == 0 || net == 2) {
                    tgt[row * 72 + col] = f2b(acc[r] + bb);
                } else {
                    float zv = acc[r] + bb - 5.f;
                    float sp = (zv > 20.f) ? zv : __logf(1.f + __expf(zv));
                    tgt[row * 72 + col] = f2b(b2f(tgt[row * 72 + col]) + sp * epr[r]);
                }
            }
        }
        __syncthreads();
    }

    // ---- P3: attention pooling over agents (wave 0 only, wave-synchronous) ----
    if (tid < 64) {
        if (tid < 32) {
            float acc = tof(att_b[0]);
            const u16* xr = nobs + tid * 72;
#pragma unroll
            for (int j = 0; j < 64; j += 8) {
                bf16x8 x = *(const bf16x8*)(xr + j);
#pragma unroll
                for (int jj = 0; jj < 8; jj++) acc = fmaf(b2f((u16)x[jj]), tof(att_w[j + jj]), acc);
            }
            plog[tid] = acc;
        }
        __builtin_amdgcn_wave_barrier();
        if (tid < 32) {
            float m = -1e30f;
            for (int a2 = 0; a2 < 32; a2++) m = fmaxf(m, plog[a2]);
            float s = 0.f;
            for (int a2 = 0; a2 < 32; a2++) s += __expf(plog[a2] - m);
            pscore[tid] = __expf(plog[tid] - m) * __builtin_amdgcn_rcpf(s);
        }
        __builtin_amdgcn_wave_barrier();
        {
            float p = 0.f;
            for (int a2 = 0; a2 < 32; a2++) p = fmaf(pscore[a2], b2f(nobs[a2 * 72 + tid]), p);
            u16 h = f2b(p);
            pooled_hi[tid] = h;
            pooled_lo[tid] = f2b(p - b2f(h));
        }
    }
    __syncthreads();

    // ---- P4: h = tanh([local | intra_obs | pooled] @ W1^T + b1) ----
#pragma unroll 1
    for (int nt = wv; nt < 16; nt += 8) {
        const int n = nt * 16 + lo16;
        f32x4 acc0 = {0.f, 0.f, 0.f, 0.f}, acc1 = {0.f, 0.f, 0.f, 0.f};
        f32x4 accp = {0.f, 0.f, 0.f, 0.f};
#pragma unroll
        for (int k0 = 0; k0 < 256; k0 += 32) {
            bf16x8 bh, bl;
            loadW<WM>(W1, WPAIR(OFF_W1), 384, n, k0 + hi * 8, bh, bl);
            bf16x8 a0 = *(const bf16x8*)(localb + lo16 * 264 + k0 + hi * 8);
            bf16x8 a1 = *(const bf16x8*)(localb + (16 + lo16) * 264 + k0 + hi * 8);
            acc0 = MFMA16(a0, bh, acc0);
            acc1 = MFMA16(a1, bh, acc1);
            if constexpr (WM != 0) { acc0 = MFMA16(a0, bl, acc0); acc1 = MFMA16(a1, bl, acc1); }
        }
#pragma unroll
        for (int k0 = 0; k0 < 64; k0 += 32) {
            bf16x8 bh, bl;
            loadW<WM>(W1, WPAIR(OFF_W1), 384, n, 256 + k0 + hi * 8, bh, bl);
            bf16x8 a0 = *(const bf16x8*)(iobs + lo16 * 72 + k0 + hi * 8);
            bf16x8 a1 = *(const bf16x8*)(iobs + (16 + lo16) * 72 + k0 + hi * 8);
            acc0 = MFMA16(a0, bh, acc0);
            acc1 = MFMA16(a1, bh, acc1);
            if constexpr (WM != 0) { acc0 = MFMA16(a0, bl, acc0); acc1 = MFMA16(a1, bl, acc1); }
        }
        // pooled segment: identical A-rows for all agents -> broadcast MFMA
#pragma unroll
        for (int k0 = 0; k0 < 64; k0 += 32) {
            bf16x8 bh, bl;
            loadW<WM>(W1, WPAIR(OFF_W1), 384, n, 320 + k0 + hi * 8, bh, bl);
            bf16x8 pa  = *(const bf16x8*)(pooled_hi + k0 + hi * 8);
            bf16x8 pal = *(const bf16x8*)(pooled_lo + k0 + hi * 8);
            accp = MFMA16(pa, bh, accp);
            accp = MFMA16(pal, bh, accp);
            if constexpr (WM != 0) accp = MFMA16(pa, bl, accp);
        }
        float bb = tof(b1[n]) + accp[0];
#pragma unroll
        for (int r = 0; r < 4; r++) {
            hb[(hi * 4 + r) * 264 + n] = f2b(fast_tanh(acc0[r] + bb));
            hb[(16 + hi * 4 + r) * 264 + n] = f2b(fast_tanh(acc1[r] + bb));
        }
    }
    __syncthreads();

    // ---- P5: h2 = tanh(h @ W2^T + b2)  (h2 overlays localb; local is dead) ----
    mdense<256, 256, 1, WM>(hb, 264, W2, WPAIR(OFF_W2), b2, localb, 264);
    __syncthreads();

    // ---- P6: heads ----
    if constexpr (WM == 2) {
        // augmented head matrix [32][256] in ws: rows 0-15 Wa, 16 Wv, 17-31 zero
        if (wv < 4) {
            const int ntU = wv & 1, half = wv >> 1;
            const u16* Hhi = wsh + OFF_WHEAD;
            const u16* Hlo = wsl + OFF_WHEAD;
            f32x4 acc = {0.f, 0.f, 0.f, 0.f};
#pragma unroll
            for (int k0 = 0; k0 < 256; k0 += 32) {
                bf16x8 bh = *(const bf16x8*)(Hhi + (size_t)(ntU * 16 + lo16) * 256 + k0 + hi * 8);
                bf16x8 bl = *(const bf16x8*)(Hlo + (size_t)(ntU * 16 + lo16) * 256 + k0 + hi * 8);
                bf16x8 a = *(const bf16x8*)(localb + (half * 16 + lo16) * 264 + k0 + hi * 8);
                acc = MFMA16(a, bh, acc);
                acc = MFMA16(a, bl, acc);
            }
#pragma unroll
            for (int r = 0; r < 4; r++) {
                const int row = half * 16 + hi * 4 + r;
                if (ntU == 0) alog[row * 18 + lo16] = acc[r] + tof(ba[lo16]);
                else if (lo16 == 0) out_v[(size_t)b * 32 + row] = fromf<T>(acc[r] + tof(bv[0]));
            }
        }
    } else {
        if (wv == 0) {          // Wa logits via MFMA (N=16 -> single n-tile)
            f32x4 acc0 = {0.f, 0.f, 0.f, 0.f}, acc1 = {0.f, 0.f, 0.f, 0.f};
#pragma unroll
            for (int k0 = 0; k0 < 256; k0 += 32) {
                bf16x8 bh, bl;
                loadW<WM>(Wa, nullptr, nullptr, 256, lo16, k0 + hi * 8, bh, bl);
                bf16x8 a0 = *(const bf16x8*)(localb + lo16 * 264 + k0 + hi * 8);
                bf16x8 a1 = *(const bf16x8*)(localb + (16 + lo16) * 264 + k0 + hi * 8);
                acc0 = MFMA16(a0, bh, acc0);
                acc1 = MFMA16(a1, bh, acc1);
                if constexpr (WM != 0) { acc0 = MFMA16(a0, bl, acc0); acc1 = MFMA16(a1, bl, acc1); }
            }
            float bb = tof(ba[lo16]);
#pragma unroll
            for (int r = 0; r < 4; r++) {
                alog[(hi * 4 + r) * 18 + lo16] = acc0[r] + bb;
                alog[(16 + hi * 4 + r) * 18 + lo16] = acc1[r] + bb;
            }
        } else if (wv == 1 && lane < 32) {   // value head (scalar fallback)
            const u16* xr = localb + lane * 264;
            float acc = tof(bv[0]);
            for (int k0 = 0; k0 < 256; k0 += 8) {
                bf16x8 x = *(const bf16x8*)(xr + k0);
#pragma unroll
                for (int j = 0; j < 8; j++) acc = fmaf(b2f((u16)x[j]), tof(Wv[k0 + j]), acc);
            }
            out_v[(size_t)b * 32 + lane] = fromf<T>(acc);
        }
    }
    __syncthreads();
    if (tid < 32) {         // log-softmax + packed store
        const float* lr = alog + tid * 18;
        float m = -1e30f;
#pragma unroll
        for (int n = 0; n < 16; n++) m = fmaxf(m, lr[n]);
        float s = 0.f;
#pragma unroll
        for (int n = 0; n < 16; n++) s += __expf(lr[n] - m);
        float lse = m + __logf(s);
        if constexpr (sizeof(T) == 2) {
            bf16x8 o0, o1;
#pragma unroll
            for (int n = 0; n < 8; n++) {
                o0[n] = (short)f2b(lr[n] - lse);
                o1[n] = (short)f2b(lr[8 + n] - lse);
            }
            bf16x8* oa = (bf16x8*)((u16*)out_a + ((size_t)b * 32 + tid) * 16);
            oa[0] = o0; oa[1] = o1;
        } else {
            float* oa = (float*)out_a + ((size_t)b * 32 + tid) * 16;
#pragma unroll
            for (int g = 0; g < 4; g++) {
                f32x4 t = {lr[4 * g] - lse, lr[4 * g + 1] - lse,
                           lr[4 * g + 2] - lse, lr[4 * g + 3] - lse};
                *(f32x4*)(oa + 4 * g) = t;
            }
        }
    }
#undef WPAIR
}

// dtype detect: fp32 misread as bf16 has uniform-random low halfwords -> some
// exponent field >= 0x90 among the first 64 halfwords w.p. ~1-1e-8. One load
// per lane + ballot (wave-uniform result).
__device__ __forceinline__ int detect_f32(const void* obs) {
    const unsigned short* u = (const unsigned short*)obs;
    int e = ((int)u[threadIdx.x & 63] >> 7) & 0xFF;
    return __ballot(e >= 0x90) != 0ull;
}

// prep: split all MFMA weights f32 -> bf16 hi/lo into workspace (f32 inputs only)
extern "C" __global__ void TeamCommAgent_prep_kernel(
    const void* obs, const void* Wl, const void* Wi, const void* Wt,
    const void* Wq, const void* Wo_, const void* W1_, const void* W2_,
    const void* Wa_, const void* Wv_, u16* ws) {
    if (!detect_f32(obs)) return;
    int i = blockIdx.x * blockDim.x + threadIdx.x;
    if (i >= WS_TOTAL) return;
    float w;
    if (i >= OFF_WHEAD) {
        int local = i - OFF_WHEAD, row = local >> 8, col = local & 255;
        w = (row < 16) ? ((const float*)Wa_)[row * 256 + col]
          : (row == 16) ? ((const float*)Wv_)[col] : 0.f;
    } else {
        const float* src; int off;
        if (i < OFF_WINTER)      { src = (const float*)Wl;  off = OFF_WLOCAL; }
        else if (i < OFF_WINTRA) { src = (const float*)Wi;  off = OFF_WINTER; }
        else if (i < OFF_WQKV)   { src = (const float*)Wt;  off = OFF_WINTRA; }
        else if (i < OFF_WO)     { src = (const float*)Wq;  off = OFF_WQKV; }
        else if (i < OFF_W1)     { src = (const float*)Wo_; off = OFF_WO; }
        else if (i < OFF_W2)     { src = (const float*)W1_; off = OFF_W1; }
        else if (i < OFF_WA)     { src = (const float*)W2_; off = OFF_W2; }
        else                     { src = (const float*)Wa_; off = OFF_WA; }
        w = src[i - off];
    }
    u16 h = f2b(w);
    ws[i] = h;
    ws[WS_TOTAL + i] = f2b(w - b2f(h));
}

extern "C" __global__ void __launch_bounds__(NT, 6)
TeamCommAgent_53077205844655_kernel(
    const void* obs, const void* eps_intra, const void* eps_inter,
    const void* W_local, const void* b_local,
    const void* W_inter, const void* b_inter,
    const void* W_intra, const void* b_intra,
    const void* Wqkv, const void* bqkv, const void* Wo, const void* bo,
    const void* att_w, const void* att_b,
    const void* W1, const void* b1, const void* W2, const void* b2,
    const void* Wa, const void* ba, const void* Wv, const void* bv,
    void* out, const u16* wsw) {
    __shared__ __align__(16) char smem[SMEM_SZ];
    if (detect_f32(obs)) {
        if (wsw) {
            body<float, 2>((const float*)obs, (const float*)eps_intra, (const float*)eps_inter,
                           (const float*)W_local, (const float*)b_local,
                           (const float*)W_inter, (const float*)b_inter,
                           (const float*)W_intra, (const float*)b_intra,
                           (const float*)Wqkv, (const float*)bqkv,
                           (const float*)Wo, (const float*)bo,
                           (const float*)att_w, (const float*)att_b,
                           (const float*)W1, (const float*)b1,
                           (const float*)W2, (const float*)b2,
                           (const float*)Wa, (const float*)ba,
                           (const float*)Wv, (const float*)bv,
                           (float*)out, (float*)out + (size_t)BB * AA_ * NACTD, smem, wsw);
        } else {
            body<float, 1>((const float*)obs, (const float*)eps_intra, (const float*)eps_inter,
                           (const float*)W_local, (const float*)b_local,
                           (const float*)W_inter, (const float*)b_inter,
                           (const float*)W_intra, (const float*)b_intra,
                           (const float*)Wqkv, (const float*)bqkv,
                           (const float*)Wo, (const float*)bo,
                           (const float*)att_w, (const float*)att_b,
                           (const float*)W1, (const float*)b1,
                           (const float*)W2, (const float*)b2,
                           (const float*)Wa, (const float*)ba,
                           (const float*)Wv, (const float*)bv,
                           (float*)out, (float*)out + (size_t)BB * AA_ * NACTD, smem, nullptr);
        }
    } else {
        body<u16, 0>((const u16*)obs, (const u16*)eps_intra, (const u16*)eps_inter,
                     (const u16*)W_local, (const u16*)b_local,
                     (const u16*)W_inter, (const u16*)b_inter,
                     (const u16*)W_intra, (const u16*)b_intra,
                     (const u16*)Wqkv, (const u16*)bqkv,
                     (const u16*)Wo, (const u16*)bo,
                     (const u16*)att_w, (const u16*)att_b,
                     (const u16*)W1, (const u16*)b1,
                     (const u16*)W2, (const u16*)b2,
                     (const u16*)Wa, (const u16*)ba,
                     (const u16*)Wv, (const u16*)bv,
                     (u16*)out, (u16*)out + (size_t)BB * AA_ * NACTD, smem, nullptr);
    }
}

extern "C" void kernel_launch(void* const* d_in, const int* in_sizes, int n_in,
                              void* d_out, int out_size, void* d_ws, size_t ws_size,
                              hipStream_t stream) {
    const bool use_ws = (d_ws != nullptr) &&
                        (ws_size >= (size_t)(2 * WS_TOTAL) * sizeof(u16));
    if (use_ws) {
        TeamCommAgent_prep_kernel<<<dim3((WS_TOTAL + 255) / 256), dim3(256), 0, stream>>>(
            d_in[0], d_in[3], d_in[5], d_in[7], d_in[9], d_in[11],
            d_in[15], d_in[17], d_in[19], d_in[21], (u16*)d_ws);
    }
    TeamCommAgent_53077205844655_kernel<<<dim3(BB), dim3(NT), 0, stream>>>(
        d_in[0], d_in[1], d_in[2], d_in[3], d_in[4], d_in[5], d_in[6],
        d_in[7], d_in[8], d_in[9], d_in[10], d_in[11], d_in[12], d_in[13],
        d_in[14], d_in[15], d_in[16], d_in[17], d_in[18], d_in[19], d_in[20],
        d_in[21], d_in[22], d_out, use_ws ? (const u16*)d_ws : nullptr);
}

// Round 9
// 477.417 us; speedup vs baseline: 1.5424x; 1.5424x over previous
//
#include <hip/hip_runtime.h>

#define BB 4096
#define AA_ 32
#define OBSD 128
#define HIDD 256
#define MSGD 64
#define NHH 4
#define DHH 16
#define NACTD 16
#define NT 512

// workspace pre-split weight layout (element offsets; hi at [i], lo at [WS_TOTAL+i])
// NOTE round 9: WM=2 reads ONLY hi (bf16 weights). lo remains in ws (unread) so the
// prep kernel and layout stay identical; WM=1 fallback still uses full hi/lo.
#define OFF_WLOCAL 0
#define OFF_WINTER 32768
#define OFF_WINTRA 40960
#define OFF_WQKV   49152
#define OFF_WO     98304
#define OFF_W1     114688
#define OFF_W2     212992
#define OFF_WA     278528
#define OFF_WHEAD  282624   // augmented head [32][256]: rows 0-15 Wa, 16 Wv, 17-31 zero
#define WS_TOTAL   290816

// LDS arena (bytes), total 49664 -> 3 blocks/CU.
//  L_LB 0      localb [32][264] 16896   (h2 in P5->P6)
//  L_IE 16896  intra_e [32][72] (nets0-1) | nobs (net2/3 -> pooling) | alog [32][18]f32 (P6)
//  L_NE 21504  inter_e [32][72] (nets2-3)
//  L_IO 26112  iobs [32][72]
//  L_QK 30720  qk [32][136] (q 0-63, k 64-127, 128-135 ZEROED pad) | xh (P1) | hb (P4->P5)
//  L_VT 39424  vT [64][40] | xl (P1, WM=1 only)
//  L_AT 44544  atto [32][72]
//  L_SC 49152  pooled_hi[64]u16, pooled_lo[64]u16, plog[32]f32, pscore[32]f32
#define L_LB 0
#define L_IE 16896
#define L_NE 21504
#define L_IO 26112
#define L_QK 30720
#define L_VT 39424
#define L_AT 44544
#define L_SC 49152
#define SMEM_SZ 49664

typedef unsigned short u16;
typedef unsigned int u32;
typedef __attribute__((ext_vector_type(8))) short bf16x8;
typedef __attribute__((ext_vector_type(4))) float f32x4;

#define MFMA16(a, b, c) __builtin_amdgcn_mfma_f32_16x16x32_bf16((a), (b), (c), 0, 0, 0)

__device__ __forceinline__ float b2f(u16 s) { return __uint_as_float((u32)s << 16); }
__device__ __forceinline__ u16 f2b(float f) {
    u32 u = __float_as_uint(f);
    u += 0x7FFFu + ((u >> 16) & 1u);   // round-to-nearest-even
    return (u16)(u >> 16);
}
__device__ __forceinline__ float tof(float x) { return x; }
__device__ __forceinline__ float tof(u16 x) { return b2f(x); }
template<typename T> __device__ __forceinline__ T fromf(float v);
template<> __device__ __forceinline__ float fromf<float>(float v) { return v; }
template<> __device__ __forceinline__ u16 fromf<u16>(float v) { return f2b(v); }

__device__ __forceinline__ bf16x8 bzero8() { bf16x8 v = {0,0,0,0,0,0,0,0}; return v; }

// fast tanh: err ~1e-6, far below bf16 storage quantum
__device__ __forceinline__ float fast_tanh(float x) {
    float ax = fabsf(x);
    float e = __expf(-2.f * ax);
    float t = (1.f - e) * __builtin_amdgcn_rcpf(1.f + e);
    return copysignf(t, x);
}

// Weight fragment loader. WM: 0 = bf16 direct (T=u16), 1 = f32 self-split (T=float,
// hi/lo 2-MFMA path), 2 = pre-split bf16 hi ONLY from workspace (1 MFMA; error
// ~= activation-bf16 storage error, threshold margin 5x).
template<int WM, typename T>
__device__ __forceinline__ void loadW(const T* Wf, const u16* Whi, const u16* Wlo,
                                      int ldw, int n, int k, bf16x8& bh, bf16x8& bl) {
    if constexpr (WM == 0) {
        bh = *(const bf16x8*)((const u16*)Wf + (size_t)n * ldw + k);
    } else if constexpr (WM == 2) {
        bh = *(const bf16x8*)(Whi + (size_t)n * ldw + k);
        (void)Wlo;
    } else {
        const float* p = (const float*)Wf + (size_t)n * ldw + k;
        f32x4 f0 = *(const f32x4*)(p);
        f32x4 f1 = *(const f32x4*)(p + 4);
#pragma unroll
        for (int j = 0; j < 8; j++) {
            float fv = (j < 4) ? f0[j] : f1[j - 4];
            u16 h = f2b(fv);
            bh[j] = (short)h;
            bl[j] = (short)f2b(fv - b2f(h));
        }
    }
}

// O[0..31][0..N) = act(X[32xK] @ W^T + bias); X in LDS bf16 (stride ldx), W [N][K].
template<int N, int K, int ACT, int WM, typename T>
__device__ __forceinline__ void mdense(const u16* X, int ldx,
                                       const T* Wf, const u16* Whi, const u16* Wlo,
                                       const T* bias, u16* O, int ldo) {
    const int tid = threadIdx.x;
    const int wv = tid >> 6, lo16 = tid & 15, hi = (tid & 63) >> 4;
#pragma unroll 1
    for (int nt = wv; nt < N / 16; nt += 8) {
        f32x4 acc0 = {0.f, 0.f, 0.f, 0.f}, acc1 = {0.f, 0.f, 0.f, 0.f};
#pragma unroll
        for (int k0 = 0; k0 < K; k0 += 32) {
            bf16x8 bh, bl;
            loadW<WM>(Wf, Whi, Wlo, K, nt * 16 + lo16, k0 + hi * 8, bh, bl);
            bf16x8 a0 = *(const bf16x8*)(X + lo16 * ldx + k0 + hi * 8);
            bf16x8 a1 = *(const bf16x8*)(X + (16 + lo16) * ldx + k0 + hi * 8);
            acc0 = MFMA16(a0, bh, acc0);
            acc1 = MFMA16(a1, bh, acc1);
            if constexpr (WM == 1) {
                acc0 = MFMA16(a0, bl, acc0);
                acc1 = MFMA16(a1, bl, acc1);
            }
        }
        float bb = tof(bias[nt * 16 + lo16]);
#pragma unroll
        for (int r = 0; r < 4; r++) {
            float v0 = acc0[r] + bb, v1 = acc1[r] + bb;
            if (ACT) { v0 = fast_tanh(v0); v1 = fast_tanh(v1); }
            O[(hi * 4 + r) * ldo + nt * 16 + lo16] = f2b(v0);
            O[(16 + hi * 4 + r) * ldo + nt * 16 + lo16] = f2b(v1);
        }
    }
}

// QKV pass for one net: q,k -> qk[row][col]; v -> transposed vT[d][row].
template<int WM, typename T>
__device__ __forceinline__ void qkv_pass(int net, const u16* xe,
                                         const T* Wqkv, const T* bqkv,
                                         const u16* wsh, const u16* wsl,
                                         u16* qk, u16* vT) {
    const int tid = threadIdx.x;
    const int wv = tid >> 6, lo16 = tid & 15, hi = (tid & 63) >> 4;
    const T* Wq = Wqkv + (size_t)net * 192 * MSGD;
    const T* bq_ = bqkv + (size_t)net * 192;
    const u16* Whi = (WM == 2) ? wsh + OFF_WQKV + net * 192 * MSGD : nullptr;
    const u16* Wlo = (WM == 2) ? wsl + OFF_WQKV + net * 192 * MSGD : nullptr;
#pragma unroll 1
    for (int nt = wv; nt < 12; nt += 8) {
        f32x4 acc0 = {0.f, 0.f, 0.f, 0.f}, acc1 = {0.f, 0.f, 0.f, 0.f};
#pragma unroll
        for (int k0 = 0; k0 < 64; k0 += 32) {
            bf16x8 bh, bl;
            loadW<WM>(Wq, Whi, Wlo, 64, nt * 16 + lo16, k0 + hi * 8, bh, bl);
            bf16x8 a0 = *(const bf16x8*)(xe + lo16 * 72 + k0 + hi * 8);
            bf16x8 a1 = *(const bf16x8*)(xe + (16 + lo16) * 72 + k0 + hi * 8);
            acc0 = MFMA16(a0, bh, acc0);
            acc1 = MFMA16(a1, bh, acc1);
            if constexpr (WM == 1) {
                acc0 = MFMA16(a0, bl, acc0);
                acc1 = MFMA16(a1, bl, acc1);
            }
        }
        float bb = tof(bq_[nt * 16 + lo16]);
        if (nt < 8) {
#pragma unroll
            for (int r = 0; r < 4; r++) {
                qk[(hi * 4 + r) * 136 + nt * 16 + lo16] = f2b(acc0[r] + bb);
                qk[(16 + hi * 4 + r) * 136 + nt * 16 + lo16] = f2b(acc1[r] + bb);
            }
        } else {
            const int d = (nt - 8) * 16 + lo16;
#pragma unroll
            for (int r = 0; r < 4; r++) {
                vT[d * 40 + hi * 4 + r] = f2b(acc0[r] + bb);
                vT[d * 40 + 16 + hi * 4 + r] = f2b(acc1[r] + bb);
            }
        }
    }
}

template<typename T, int WM>
__device__ void body(const T* obs, const T* eps_intra, const T* eps_inter,
                     const T* W_local, const T* b_local,
                     const T* W_inter, const T* b_inter,
                     const T* W_intra, const T* b_intra,
                     const T* Wqkv, const T* bqkv, const T* Wo, const T* bo,
                     const T* att_w, const T* att_b,
                     const T* W1, const T* b1, const T* W2, const T* b2,
                     const T* Wa, const T* ba, const T* Wv, const T* bv,
                     T* out_a, T* out_v, char* smem, const u16* wsw) {
    constexpr bool XSPLIT = (sizeof(T) == 4) && (WM == 1);  // obs hi/lo only in fallback
    const int tid = threadIdx.x;
    const int b = blockIdx.x;
    const int wv = tid >> 6, lane = tid & 63, lo16 = lane & 15, hi = lane >> 4;

    const u16* wsh = wsw;
    const u16* wsl = (WM == 2) ? wsw + WS_TOTAL : nullptr;
#define WPAIR(OFF) ((WM == 2) ? wsh + (OFF) : nullptr), ((WM == 2) ? wsl + (OFF) : nullptr)

    u16* localb    = (u16*)(smem + L_LB);
    u16* intra_e   = (u16*)(smem + L_IE);
    u16* nobs      = (u16*)(smem + L_IE);
    float* alog    = (float*)(smem + L_IE);
    u16* inter_e   = (u16*)(smem + L_NE);
    u16* iobs      = (u16*)(smem + L_IO);
    u16* qk        = (u16*)(smem + L_QK);
    u16* xh        = (u16*)(smem + L_QK);
    u16* hb        = (u16*)(smem + L_QK);
    u16* vT        = (u16*)(smem + L_VT);
    u16* xl        = (u16*)(smem + L_VT);
    u16* atto      = (u16*)(smem + L_AT);
    u16* pooled_hi = (u16*)(smem + L_SC);
    u16* pooled_lo = (u16*)(smem + L_SC + 128);
    float* plog    = (float*)(smem + L_SC + 256);
    float* pscore  = (float*)(smem + L_SC + 384);

    // ---- P1a: stage obs -> LDS bf16 (hi + lo residual only in WM=1 fallback) ----
    {
        const T* ob = obs + (size_t)b * (AA_ * OBSD);
        const int i = tid;               // 512 groups of 8 == exactly NT
        const int row = i >> 4, col = (i & 15) * 8;
        if constexpr (sizeof(T) == 4) {
            f32x4 f0 = __builtin_nontemporal_load((const f32x4*)(ob + i * 8));
            f32x4 f1 = __builtin_nontemporal_load((const f32x4*)(ob + i * 8) + 1);
            bf16x8 vh, vl;
#pragma unroll
            for (int j = 0; j < 8; j++) {
                float fv = (j < 4) ? f0[j] : f1[j - 4];
                u16 h = f2b(fv);
                vh[j] = (short)h;
                vl[j] = (short)f2b(fv - b2f(h));
            }
            *(bf16x8*)(xh + row * 136 + col) = vh;
            if constexpr (XSPLIT) *(bf16x8*)(xl + row * 136 + col) = vl;
        } else {
            bf16x8 v = __builtin_nontemporal_load((const bf16x8*)(ob + i * 8));
            *(bf16x8*)(xh + row * 136 + col) = v;
        }
        // CRITICAL: zero qk/xh pad columns 128..135. The fused-scores phase reads
        // A-fragments unconditionally (head 3, hi>=2 lanes hit these columns with
        // B=0); uninitialized LDS could decode as NaN/Inf -> 0*NaN = NaN in MFMA.
        // Nothing writes these pads during P2, so one zeroing persists for all nets.
        if (tid < 32) *(bf16x8*)(xh + tid * 136 + 128) = bzero8();
    }
    __syncthreads();

    // ---- P1b: local/intra/inter embeddings (24 tile-units over 8 waves) ----
#pragma unroll 1
    for (int u = wv; u < 24; u += 8) {
        const T *Wf, *bias; const u16 *Whi = nullptr, *Wlo = nullptr; u16* O; int ldo, nt;
        if (u < 16)      { Wf = W_local; bias = b_local; O = localb;  ldo = 264; nt = u;
                           if (WM == 2) { Whi = wsh + OFF_WLOCAL; Wlo = wsl + OFF_WLOCAL; } }
        else if (u < 20) { Wf = W_intra; bias = b_intra; O = intra_e; ldo = 72;  nt = u - 16;
                           if (WM == 2) { Whi = wsh + OFF_WINTRA; Wlo = wsl + OFF_WINTRA; } }
        else             { Wf = W_inter; bias = b_inter; O = inter_e; ldo = 72;  nt = u - 20;
                           if (WM == 2) { Whi = wsh + OFF_WINTER; Wlo = wsl + OFF_WINTER; } }
        f32x4 acc0 = {0.f, 0.f, 0.f, 0.f}, acc1 = {0.f, 0.f, 0.f, 0.f};
#pragma unroll
        for (int k0 = 0; k0 < OBSD; k0 += 32) {
            bf16x8 bh, bl;
            loadW<WM>(Wf, Whi, Wlo, OBSD, nt * 16 + lo16, k0 + hi * 8, bh, bl);
            bf16x8 a0 = *(const bf16x8*)(xh + lo16 * 136 + k0 + hi * 8);
            bf16x8 a1 = *(const bf16x8*)(xh + (16 + lo16) * 136 + k0 + hi * 8);
            acc0 = MFMA16(a0, bh, acc0);
            acc1 = MFMA16(a1, bh, acc1);
            if constexpr (WM == 1) {
                acc0 = MFMA16(a0, bl, acc0);
                acc1 = MFMA16(a1, bl, acc1);
            }
            if constexpr (XSPLIT) {
                bf16x8 l0 = *(const bf16x8*)(xl + lo16 * 136 + k0 + hi * 8);
                bf16x8 l1 = *(const bf16x8*)(xl + (16 + lo16) * 136 + k0 + hi * 8);
                acc0 = MFMA16(l0, bh, acc0);
                acc1 = MFMA16(l1, bh, acc1);
            }
        }
        float bb = tof(bias[nt * 16 + lo16]);
#pragma unroll
        for (int r = 0; r < 4; r++) {
            O[(hi * 4 + r) * ldo + nt * 16 + lo16] = f2b(fast_tanh(acc0[r] + bb));
            O[(16 + hi * 4 + r) * ldo + nt * 16 + lo16] = f2b(fast_tanh(acc1[r] + bb));
        }
    }
    __syncthreads();

    // ==== P2: 4 MHA nets (0:intra_mu 1:intra_std 2:inter_mu 3:inter_std). ====
#pragma unroll 1
    for (int net = 0; net < 4; net++) {
        qkv_pass<WM>(net, (net < 2) ? intra_e : inter_e, Wqkv, bqkv, wsh, wsl, qk, vT);
        __syncthreads();

        // fused scores + softmax + PV, one phase, no LDS P-matrix.
        // Transposed QK^T: mfma(K,Q) -> lane holds S[q=lo16][k in {4hi+r,16+4hi+r}].
        float epr[4] = {0.f, 0.f, 0.f, 0.f};
        {
            const int h = wv >> 1, mt = wv & 1;
            // prefetch eps for std-net outproj (consumed next phase)
            if (net == 1 || net == 3) {
                const T* epsb = ((net == 1) ? eps_intra : eps_inter) + (size_t)b * (AA_ * MSGD);
                const int ntU = wv & 3, half = wv >> 2, col = ntU * 16 + lo16;
#pragma unroll
                for (int r = 0; r < 4; r++)
                    epr[r] = tof(__builtin_nontemporal_load(epsb + (half * 16 + hi * 4 + r) * MSGD + col));
            }
            bf16x8 a0 = *(const bf16x8*)(qk + lo16 * 136 + 64 + h * 16 + hi * 8);
            bf16x8 a1 = *(const bf16x8*)(qk + (16 + lo16) * 136 + 64 + h * 16 + hi * 8);
            bf16x8 bq = bzero8();          // zero-pad dh 16->32 (B=0 kills k>=16 terms)
            if (hi < 2) bq = *(const bf16x8*)(qk + (mt * 16 + lo16) * 136 + h * 16 + hi * 8);
            f32x4 z = {0.f, 0.f, 0.f, 0.f};
            f32x4 sc0 = MFMA16(a0, bq, z);
            f32x4 sc1 = MFMA16(a1, bq, z);
            // softmax over k for row q=lo16: 8 in-lane values + 2 shfl_xor hops
            float v0[4], v1[4];
#pragma unroll
            for (int r = 0; r < 4; r++) { v0[r] = sc0[r] * 0.25f; v1[r] = sc1[r] * 0.25f; }
            float m = fmaxf(fmaxf(fmaxf(v0[0], v0[1]), fmaxf(v0[2], v0[3])),
                            fmaxf(fmaxf(v1[0], v1[1]), fmaxf(v1[2], v1[3])));
            m = fmaxf(m, __shfl_xor(m, 16));
            m = fmaxf(m, __shfl_xor(m, 32));
            float e0[4], e1[4], s = 0.f;
#pragma unroll
            for (int r = 0; r < 4; r++) {
                e0[r] = __expf(v0[r] - m); e1[r] = __expf(v1[r] - m);
                s += e0[r] + e1[r];
            }
            s += __shfl_xor(s, 16);
            s += __shfl_xor(s, 32);
            float inv = __builtin_amdgcn_rcpf(s);
            u32 pk0 = (u32)f2b(e0[0] * inv) | ((u32)f2b(e0[1] * inv) << 16);
            u32 pk1 = (u32)f2b(e0[2] * inv) | ((u32)f2b(e0[3] * inv) << 16);
            u32 pk2 = (u32)f2b(e1[0] * inv) | ((u32)f2b(e1[1] * inv) << 16);
            u32 pk3 = (u32)f2b(e1[2] * inv) | ((u32)f2b(e1[3] * inv) << 16);
            // assemble PV A-fragment: lane (q=lo16, hi) needs P[q][8hi..8hi+7]
            const int sA = (((hi * 2) & 3) << 4) | lo16;
            const int sB = sA + 16;
            u32 wA0 = __shfl(pk0, sA), wA1 = __shfl(pk1, sA);
            u32 wB0 = __shfl(pk0, sB), wB1 = __shfl(pk1, sB);
            u32 xA0 = __shfl(pk2, sA), xA1 = __shfl(pk3, sA);
            u32 xB0 = __shfl(pk2, sB), xB1 = __shfl(pk3, sB);
            const bool lo = (hi < 2);
            union { u32 w[4]; bf16x8 v; } pu;
            pu.w[0] = lo ? wA0 : xA0;
            pu.w[1] = lo ? wA1 : xA1;
            pu.w[2] = lo ? wB0 : xB0;
            pu.w[3] = lo ? wB1 : xB1;
            bf16x8 bv_ = *(const bf16x8*)(vT + (h * 16 + lo16) * 40 + hi * 8);
            f32x4 o = MFMA16(pu.v, bv_, z);
#pragma unroll
            for (int r = 0; r < 4; r++)
                atto[(mt * 16 + hi * 4 + r) * 72 + h * 16 + lo16] = f2b(o[r]);
        }
        __syncthreads();

        // out projection; mu nets write raw, std nets merge softplus*eps into target
        {
            const T* Won = Wo + (size_t)net * MSGD * MSGD;
            const T* bon = bo + (size_t)net * MSGD;
            const u16* Ohi = (WM == 2) ? wsh + OFF_WO + net * 4096 : nullptr;
            const u16* Olo = (WM == 2) ? wsl + OFF_WO + net * 4096 : nullptr;
            const int ntU = wv & 3, half = wv >> 2, col = ntU * 16 + lo16;
            f32x4 acc = {0.f, 0.f, 0.f, 0.f};
#pragma unroll
            for (int k0 = 0; k0 < 64; k0 += 32) {
                bf16x8 bh, bl;
                loadW<WM>(Won, Ohi, Olo, 64, col, k0 + hi * 8, bh, bl);
                bf16x8 a = *(const bf16x8*)(atto + (half * 16 + lo16) * 72 + k0 + hi * 8);
                acc = MFMA16(a, bh, acc);
                if constexpr (WM == 1) acc = MFMA16(a, bl, acc);
            }
            float bb = tof(bon[col]);
            u16* tgt = (net < 2) ? iobs : nobs;
#pragma unroll
            for (int r = 0; r < 4; r++) {
                const int row = half * 16 + hi * 4 + r;
                if (net == 0 || net == 2) {
                    tgt[row * 72 + col] = f2b(acc[r] + bb);
                } else {
                    float zv = acc[r] + bb - 5.f;
                    float sp = (zv > 20.f) ? zv : __logf(1.f + __expf(zv));
                    tgt[row * 72 + col] = f2b(b2f(tgt[row * 72 + col]) + sp * epr[r]);
                }
            }
        }
        __syncthreads();
    }

    // ---- P3: attention pooling over agents (wave 0 only, wave-synchronous) ----
    if (tid < 64) {
        if (tid < 32) {
            float acc = tof(att_b[0]);
            const u16* xr = nobs + tid * 72;
#pragma unroll
            for (int j = 0; j < 64; j += 8) {
                bf16x8 x = *(const bf16x8*)(xr + j);
#pragma unroll
                for (int jj = 0; jj < 8; jj++) acc = fmaf(b2f((u16)x[jj]), tof(att_w[j + jj]), acc);
            }
            plog[tid] = acc;
        }
        __builtin_amdgcn_wave_barrier();
        if (tid < 32) {
            float m = -1e30f;
            for (int a2 = 0; a2 < 32; a2++) m = fmaxf(m, plog[a2]);
            float s = 0.f;
            for (int a2 = 0; a2 < 32; a2++) s += __expf(plog[a2] - m);
            pscore[tid] = __expf(plog[tid] - m) * __builtin_amdgcn_rcpf(s);
        }
        __builtin_amdgcn_wave_barrier();
        {
            float p = 0.f;
            for (int a2 = 0; a2 < 32; a2++) p = fmaf(pscore[a2], b2f(nobs[a2 * 72 + tid]), p);
            u16 h = f2b(p);
            pooled_hi[tid] = h;
            pooled_lo[tid] = f2b(p - b2f(h));
        }
    }
    __syncthreads();

    // ---- P4: h = tanh([local | intra_obs | pooled] @ W1^T + b1) ----
#pragma unroll 1
    for (int nt = wv; nt < 16; nt += 8) {
        const int n = nt * 16 + lo16;
        f32x4 acc0 = {0.f, 0.f, 0.f, 0.f}, acc1 = {0.f, 0.f, 0.f, 0.f};
        f32x4 accp = {0.f, 0.f, 0.f, 0.f};
#pragma unroll
        for (int k0 = 0; k0 < 256; k0 += 32) {
            bf16x8 bh, bl;
            loadW<WM>(W1, WPAIR(OFF_W1), 384, n, k0 + hi * 8, bh, bl);
            bf16x8 a0 = *(const bf16x8*)(localb + lo16 * 264 + k0 + hi * 8);
            bf16x8 a1 = *(const bf16x8*)(localb + (16 + lo16) * 264 + k0 + hi * 8);
            acc0 = MFMA16(a0, bh, acc0);
            acc1 = MFMA16(a1, bh, acc1);
            if constexpr (WM == 1) { acc0 = MFMA16(a0, bl, acc0); acc1 = MFMA16(a1, bl, acc1); }
        }
#pragma unroll
        for (int k0 = 0; k0 < 64; k0 += 32) {
            bf16x8 bh, bl;
            loadW<WM>(W1, WPAIR(OFF_W1), 384, n, 256 + k0 + hi * 8, bh, bl);
            bf16x8 a0 = *(const bf16x8*)(iobs + lo16 * 72 + k0 + hi * 8);
            bf16x8 a1 = *(const bf16x8*)(iobs + (16 + lo16) * 72 + k0 + hi * 8);
            acc0 = MFMA16(a0, bh, acc0);
            acc1 = MFMA16(a1, bh, acc1);
            if constexpr (WM == 1) { acc0 = MFMA16(a0, bl, acc0); acc1 = MFMA16(a1, bl, acc1); }
        }
        // pooled segment: identical A-rows for all agents -> broadcast MFMA.
        // pooled hi/lo kept (in-LDS data, zero extra global loads).
#pragma unroll
        for (int k0 = 0; k0 < 64; k0 += 32) {
            bf16x8 bh, bl;
            loadW<WM>(W1, WPAIR(OFF_W1), 384, n, 320 + k0 + hi * 8, bh, bl);
            bf16x8 pa  = *(const bf16x8*)(pooled_hi + k0 + hi * 8);
            bf16x8 pal = *(const bf16x8*)(pooled_lo + k0 + hi * 8);
            accp = MFMA16(pa, bh, accp);
            accp = MFMA16(pal, bh, accp);
            if constexpr (WM == 1) accp = MFMA16(pa, bl, accp);
        }
        float bb = tof(b1[n]) + accp[0];
#pragma unroll
        for (int r = 0; r < 4; r++) {
            hb[(hi * 4 + r) * 264 + n] = f2b(fast_tanh(acc0[r] + bb));
            hb[(16 + hi * 4 + r) * 264 + n] = f2b(fast_tanh(acc1[r] + bb));
        }
    }
    __syncthreads();

    // ---- P5: h2 = tanh(h @ W2^T + b2)  (h2 overlays localb; local is dead) ----
    mdense<256, 256, 1, WM>(hb, 264, W2, WPAIR(OFF_W2), b2, localb, 264);
    __syncthreads();

    // ---- P6: heads ----
    if constexpr (WM == 2) {
        // augmented head matrix [32][256] in ws: rows 0-15 Wa, 16 Wv, 17-31 zero
        if (wv < 4) {
            const int ntU = wv & 1, half = wv >> 1;
            const u16* Hhi = wsh + OFF_WHEAD;
            f32x4 acc = {0.f, 0.f, 0.f, 0.f};
#pragma unroll
            for (int k0 = 0; k0 < 256; k0 += 32) {
                bf16x8 bh = *(const bf16x8*)(Hhi + (size_t)(ntU * 16 + lo16) * 256 + k0 + hi * 8);
                bf16x8 a = *(const bf16x8*)(localb + (half * 16 + lo16) * 264 + k0 + hi * 8);
                acc = MFMA16(a, bh, acc);
            }
#pragma unroll
            for (int r = 0; r < 4; r++) {
                const int row = half * 16 + hi * 4 + r;
                if (ntU == 0) alog[row * 18 + lo16] = acc[r] + tof(ba[lo16]);
                else if (lo16 == 0) out_v[(size_t)b * 32 + row] = fromf<T>(acc[r] + tof(bv[0]));
            }
        }
    } else {
        if (wv == 0) {          // Wa logits via MFMA (N=16 -> single n-tile)
            f32x4 acc0 = {0.f, 0.f, 0.f, 0.f}, acc1 = {0.f, 0.f, 0.f, 0.f};
#pragma unroll
            for (int k0 = 0; k0 < 256; k0 += 32) {
                bf16x8 bh, bl;
                loadW<WM>(Wa, nullptr, nullptr, 256, lo16, k0 + hi * 8, bh, bl);
                bf16x8 a0 = *(const bf16x8*)(localb + lo16 * 264 + k0 + hi * 8);
                bf16x8 a1 = *(const bf16x8*)(localb + (16 + lo16) * 264 + k0 + hi * 8);
                acc0 = MFMA16(a0, bh, acc0);
                acc1 = MFMA16(a1, bh, acc1);
                if constexpr (WM == 1) { acc0 = MFMA16(a0, bl, acc0); acc1 = MFMA16(a1, bl, acc1); }
            }
            float bb = tof(ba[lo16]);
#pragma unroll
            for (int r = 0; r < 4; r++) {
                alog[(hi * 4 + r) * 18 + lo16] = acc0[r] + bb;
                alog[(16 + hi * 4 + r) * 18 + lo16] = acc1[r] + bb;
            }
        } else if (wv == 1 && lane < 32) {   // value head (scalar fallback)
            const u16* xr = localb + lane * 264;
            float acc = tof(bv[0]);
            for (int k0 = 0; k0 < 256; k0 += 8) {
                bf16x8 x = *(const bf16x8*)(xr + k0);
#pragma unroll
                for (int j = 0; j < 8; j++) acc = fmaf(b2f((u16)x[j]), tof(Wv[k0 + j]), acc);
            }
            out_v[(size_t)b * 32 + lane] = fromf<T>(acc);
        }
    }
    __syncthreads();
    if (tid < 32) {         // log-softmax + packed store
        const float* lr = alog + tid * 18;
        float m = -1e30f;
#pragma unroll
        for (int n = 0; n < 16; n++) m = fmaxf(m, lr[n]);
        float s = 0.f;
#pragma unroll
        for (int n = 0; n < 16; n++) s += __expf(lr[n] - m);
        float lse = m + __logf(s);
        if constexpr (sizeof(T) == 2) {
            bf16x8 o0, o1;
#pragma unroll
            for (int n = 0; n < 8; n++) {
                o0[n] = (short)f2b(lr[n] - lse);
                o1[n] = (short)f2b(lr[8 + n] - lse);
            }
            bf16x8* oa = (bf16x8*)((u16*)out_a + ((size_t)b * 32 + tid) * 16);
            oa[0] = o0; oa[1] = o1;
        } else {
            float* oa = (float*)out_a + ((size_t)b * 32 + tid) * 16;
#pragma unroll
            for (int g = 0; g < 4; g++) {
                f32x4 t = {lr[4 * g] - lse, lr[4 * g + 1] - lse,
                           lr[4 * g + 2] - lse, lr[4 * g + 3] - lse};
                *(f32x4*)(oa + 4 * g) = t;
            }
        }
    }
#undef WPAIR
}

// dtype detect: fp32 misread as bf16 has uniform-random low halfwords -> some
// exponent field >= 0x90 among the first 64 halfwords w.p. ~1-1e-8. One load
// per lane + ballot (wave-uniform result).
__device__ __forceinline__ int detect_f32(const void* obs) {
    const unsigned short* u = (const unsigned short*)obs;
    int e = ((int)u[threadIdx.x & 63] >> 7) & 0xFF;
    return __ballot(e >= 0x90) != 0ull;
}

// prep: split all MFMA weights f32 -> bf16 hi/lo into workspace (f32 inputs only).
// lo halves are written but unread by the WM=2 path (kept for layout stability).
extern "C" __global__ void TeamCommAgent_prep_kernel(
    const void* obs, const void* Wl, const void* Wi, const void* Wt,
    const void* Wq, const void* Wo_, const void* W1_, const void* W2_,
    const void* Wa_, const void* Wv_, u16* ws) {
    if (!detect_f32(obs)) return;
    int i = blockIdx.x * blockDim.x + threadIdx.x;
    if (i >= WS_TOTAL) return;
    float w;
    if (i >= OFF_WHEAD) {
        int local = i - OFF_WHEAD, row = local >> 8, col = local & 255;
        w = (row < 16) ? ((const float*)Wa_)[row * 256 + col]
          : (row == 16) ? ((const float*)Wv_)[col] : 0.f;
    } else {
        const float* src; int off;
        if (i < OFF_WINTER)      { src = (const float*)Wl;  off = OFF_WLOCAL; }
        else if (i < OFF_WINTRA) { src = (const float*)Wi;  off = OFF_WINTER; }
        else if (i < OFF_WQKV)   { src = (const float*)Wt;  off = OFF_WINTRA; }
        else if (i < OFF_WO)     { src = (const float*)Wq;  off = OFF_WQKV; }
        else if (i < OFF_W1)     { src = (const float*)Wo_; off = OFF_WO; }
        else if (i < OFF_W2)     { src = (const float*)W1_; off = OFF_W1; }
        else if (i < OFF_WA)     { src = (const float*)W2_; off = OFF_W2; }
        else                     { src = (const float*)Wa_; off = OFF_WA; }
        w = src[i - off];
    }
    u16 h = f2b(w);
    ws[i] = h;
    ws[WS_TOTAL + i] = f2b(w - b2f(h));
}

extern "C" __global__ void __launch_bounds__(NT, 6)
TeamCommAgent_53077205844655_kernel(
    const void* obs, const void* eps_intra, const void* eps_inter,
    const void* W_local, const void* b_local,
    const void* W_inter, const void* b_inter,
    const void* W_intra, const void* b_intra,
    const void* Wqkv, const void* bqkv, const void* Wo, const void* bo,
    const void* att_w, const void* att_b,
    const void* W1, const void* b1, const void* W2, const void* b2,
    const void* Wa, const void* ba, const void* Wv, const void* bv,
    void* out, const u16* wsw) {
    __shared__ __align__(16) char smem[SMEM_SZ];
    if (detect_f32(obs)) {
        if (wsw) {
            body<float, 2>((const float*)obs, (const float*)eps_intra, (const float*)eps_inter,
                           (const float*)W_local, (const float*)b_local,
                           (const float*)W_inter, (const float*)b_inter,
                           (const float*)W_intra, (const float*)b_intra,
                           (const float*)Wqkv, (const float*)bqkv,
                           (const float*)Wo, (const float*)bo,
                           (const float*)att_w, (const float*)att_b,
                           (const float*)W1, (const float*)b1,
                           (const float*)W2, (const float*)b2,
                           (const float*)Wa, (const float*)ba,
                           (const float*)Wv, (const float*)bv,
                           (float*)out, (float*)out + (size_t)BB * AA_ * NACTD, smem, wsw);
        } else {
            body<float, 1>((const float*)obs, (const float*)eps_intra, (const float*)eps_inter,
                           (const float*)W_local, (const float*)b_local,
                           (const float*)W_inter, (const float*)b_inter,
                           (const float*)W_intra, (const float*)b_intra,
                           (const float*)Wqkv, (const float*)bqkv,
                           (const float*)Wo, (const float*)bo,
                           (const float*)att_w, (const float*)att_b,
                           (const float*)W1, (const float*)b1,
                           (const float*)W2, (const float*)b2,
                           (const float*)Wa, (const float*)ba,
                           (const float*)Wv, (const float*)bv,
                           (float*)out, (float*)out + (size_t)BB * AA_ * NACTD, smem, nullptr);
        }
    } else {
        body<u16, 0>((const u16*)obs, (const u16*)eps_intra, (const u16*)eps_inter,
                     (const u16*)W_local, (const u16*)b_local,
                     (const u16*)W_inter, (const u16*)b_inter,
                     (const u16*)W_intra, (const u16*)b_intra,
                     (const u16*)Wqkv, (const u16*)bqkv,
                     (const u16*)Wo, (const u16*)bo,
                     (const u16*)att_w, (const u16*)att_b,
                     (const u16*)W1, (const u16*)b1,
                     (const u16*)W2, (const u16*)b2,
                     (const u16*)Wa, (const u16*)ba,
                     (const u16*)Wv, (const u16*)bv,
                     (u16*)out, (u16*)out + (size_t)BB * AA_ * NACTD, smem, nullptr);
    }
}

extern "C" void kernel_launch(void* const* d_in, const int* in_sizes, int n_in,
                              void* d_out, int out_size, void* d_ws, size_t ws_size,
                              hipStream_t stream) {
    const bool use_ws = (d_ws != nullptr) &&
                        (ws_size >= (size_t)(2 * WS_TOTAL) * sizeof(u16));
    if (use_ws) {
        TeamCommAgent_prep_kernel<<<dim3((WS_TOTAL + 255) / 256), dim3(256), 0, stream>>>(
            d_in[0], d_in[3], d_in[5], d_in[7], d_in[9], d_in[11],
            d_in[15], d_in[17], d_in[19], d_in[21], (u16*)d_ws);
    }
    TeamCommAgent_53077205844655_kernel<<<dim3(BB), dim3(NT), 0, stream>>>(
        d_in[0], d_in[1], d_in[2], d_in[3], d_in[4], d_in[5], d_in[6],
        d_in[7], d_in[8], d_in[9], d_in[10], d_in[11], d_in[12], d_in[13],
        d_in[14], d_in[15], d_in[16], d_in[17], d_in[18], d_in[19], d_in[20],
        d_in[21], d_in[22], d_out, use_ws ? (const u16*)d_ws : nullptr);
}